// Round 10
// baseline (214.567 us; speedup 1.0000x reference)
//
#include <hip/hip_runtime.h>
#include <hip/hip_bf16.h>

#define NEG_SLOPE 0.2f

typedef _Float16 half8 __attribute__((ext_vector_type(8)));
typedef _Float16 half4v __attribute__((ext_vector_type(4)));
typedef _Float16 half2v __attribute__((ext_vector_type(2)));
typedef float floatx4 __attribute__((ext_vector_type(4)));
typedef float floatx2 __attribute__((ext_vector_type(2)));

// ---------------------------------------------------------------- CSR build
__global__ void k_hist(const int* __restrict__ dst, int E, int n, int* __restrict__ deg) {
    int e = blockIdx.x * blockDim.x + threadIdx.x;
    int ET = E + n;
    if (e >= ET) return;
    int d = (e < E) ? dst[e] : (e - E);   // self-loops appended
    atomicAdd(&deg[d], 1);
}

// phase 1: per-block sums (coalesced)
__global__ void k_scan1(const int* __restrict__ deg, int* __restrict__ bsum, int n) {
    __shared__ int red[256];
    int t = threadIdx.x, b = blockIdx.x;
    int i = b * 256 + t;
    red[t] = (i < n) ? deg[i] : 0;
    __syncthreads();
    for (int off = 128; off; off >>= 1) {
        if (t < off) red[t] += red[t + off];
        __syncthreads();
    }
    if (t == 0) bsum[b] = red[0];
}

// phase 2+3 fused: every block prefixes the (<=256) block sums itself, then
// does its local inclusive scan + offset -> rowptr/cursor.
__global__ void k_scan3(const int* __restrict__ deg, const int* __restrict__ bsum,
                        int nb, int* __restrict__ rowptr, int* __restrict__ cursor,
                        int n) {
    __shared__ int s[256];
    int t = threadIdx.x, b = blockIdx.x;
    s[t] = (t < nb) ? bsum[t] : 0;
    __syncthreads();
    for (int off = 1; off < 256; off <<= 1) {
        int v = (t >= off) ? s[t - off] : 0;
        __syncthreads();
        s[t] += v;
        __syncthreads();
    }
    int base = (b == 0) ? 0 : s[b - 1];
    __syncthreads();
    int i = b * 256 + t;
    int v = (i < n) ? deg[i] : 0;
    s[t] = v;
    __syncthreads();
    for (int off = 1; off < 256; off <<= 1) {
        int u = (t >= off) ? s[t - off] : 0;
        __syncthreads();
        s[t] += u;
        __syncthreads();
    }
    int incl = s[t];
    if (i < n) {
        rowptr[i] = base + incl - v;
        cursor[i] = base + incl - v;
        if (i == n - 1) rowptr[n] = base + incl;
    }
}

__global__ void k_scatter(const int* __restrict__ src, const int* __restrict__ dst,
                          int E, int n, int* __restrict__ cursor,
                          int* __restrict__ csr_src) {
    int e = blockIdx.x * blockDim.x + threadIdx.x;
    int ET = E + n;
    if (e >= ET) return;
    int s = (e < E) ? src[e] : (e - E);
    int d = (e < E) ? dst[e] : (e - E);
    int pos = atomicAdd(&cursor[d], 1);
    csr_src[pos] = s;
}

// --------------------- fused weight prep: W1t, W2t transposes + vs/vd vectors
__global__ void k_wprep(const float* __restrict__ W1, const float* __restrict__ W2,
                        const float* __restrict__ as1, const float* __restrict__ ad1,
                        const float* __restrict__ as2, const float* __restrict__ ad2,
                        _Float16* __restrict__ w1t, _Float16* __restrict__ w2t,
                        float* __restrict__ vs1, float* __restrict__ vd1,
                        float* __restrict__ vs2, float* __restrict__ vd2) {
    int b = blockIdx.x;
    if (b < 384) {                       // W1[128][768] -> w1t[768][128]
        int i = b * 256 + threadIdx.x;
        int c = i / 128, r = i % 128;
        w1t[i] = (_Float16)W1[(size_t)r * 768 + c];
    } else if (b < 1536) {               // W2[768][384] -> w2t[384][768]
        int i = (b - 384) * 256 + threadIdx.x;
        int c = i / 768, r = i % 768;
        w2t[i] = (_Float16)W2[(size_t)r * 384 + c];
    } else if (b < 1538) {               // vs1/vd1 (384 outputs)
        int t = (b - 1536) * 256 + threadIdx.x;
        if (t < 384) {
            int h = t >> 7, k = t & 127;
            const float* wr = W1 + (size_t)k * 768 + h * 256;
            const float* ar = as1 + h * 256;
            const float* dr = ad1 + h * 256;
            float s = 0.f, d = 0.f;
            for (int c = 0; c < 256; ++c) { float wv = wr[c]; s += wv * ar[c]; d += wv * dr[c]; }
            vs1[t] = s; vd1[t] = d;
        }
    } else {                             // vs2/vd2 (768 outputs)
        int t = (b - 1538) * 256 + threadIdx.x;
        if (t < 768) {
            const float* wr = W2 + (size_t)t * 384;
            float s = 0.f, d = 0.f;
            for (int c = 0; c < 384; ++c) { float wv = wr[c]; s += wv * as2[c]; d += wv * ad2[c]; }
            vs2[t] = s; vd2[t] = d;
        }
    }
}

// -------------------------- fused x fp32->fp16 + layer-1 logits (one pass)
__global__ __launch_bounds__(256) void k_prep1(const float* __restrict__ x,
        _Float16* __restrict__ xh, const float* __restrict__ vs,
        const float* __restrict__ vd, float* __restrict__ al_s,
        float* __restrict__ al_d, int n) {
    int wid = (blockIdx.x * blockDim.x + threadIdx.x) >> 6;
    int lane = threadIdx.x & 63;
    if (wid >= n) return;
    float2 f = *(const float2*)(x + (size_t)wid * 128 + lane * 2);
    half2v hv; hv[0] = (_Float16)f.x; hv[1] = (_Float16)f.y;
    *(half2v*)(xh + (size_t)wid * 128 + lane * 2) = hv;
    float aS[3], aD[3];
#pragma unroll
    for (int hh = 0; hh < 3; ++hh) {
        floatx2 v = *(const floatx2*)(vs + hh * 128 + lane * 2);
        floatx2 d = *(const floatx2*)(vd + hh * 128 + lane * 2);
        aS[hh] = f.x * v[0] + f.y * v[1];
        aD[hh] = f.x * d[0] + f.y * d[1];
    }
#pragma unroll
    for (int hh = 0; hh < 3; ++hh)
#pragma unroll
        for (int off = 32; off; off >>= 1) {
            aS[hh] += __shfl_xor(aS[hh], off);
            aD[hh] += __shfl_xor(aD[hh], off);
        }
    if (lane == 0) {
#pragma unroll
        for (int hh = 0; hh < 3; ++hh) { al_s[wid * 3 + hh] = aS[hh]; al_d[wid * 3 + hh] = aD[hh]; }
    }
}

// ---------------------- layer-1 aggregation in INPUT space, inline edge exp
__global__ __launch_bounds__(256) void k_aggx(const _Float16* __restrict__ xh,
                                              const float* __restrict__ al_s,
                                              const float* __restrict__ al_d,
                                              const int* __restrict__ rowptr,
                                              const int* __restrict__ csr_src,
                                              _Float16* __restrict__ xagg,
                                              int n) {
    int wid = (blockIdx.x * blockDim.x + threadIdx.x) >> 6;
    int lane = threadIdx.x & 63;
    if (wid >= n) return;
    int beg = rowptr[wid], end = rowptr[wid + 1];
    int slot = lane >> 4;     // 0..3  (edge within group)
    int chunk = lane & 15;    // channel chunk

    float ald0 = al_d[wid * 3 + 0], ald1 = al_d[wid * 3 + 1], ald2 = al_d[wid * 3 + 2];

    float acc0[8] = {}, acc1[8] = {}, acc2[8] = {};
    float sw0 = 0.f, sw1 = 0.f, sw2 = 0.f;

    for (int base = beg; base < end; base += 8) {
        int eA = base + slot, eB = base + 4 + slot;
        bool vA = eA < end, vB = eB < end;
        int sA = vA ? csr_src[eA] : 0;
        int sB = vB ? csr_src[eB] : 0;
        float wA0 = 0.f, wA1 = 0.f, wA2 = 0.f, wB0 = 0.f, wB1 = 0.f, wB2 = 0.f;
        if (vA) {
            float e0 = al_s[sA * 3 + 0] + ald0; e0 = e0 > 0.f ? e0 : NEG_SLOPE * e0;
            float e1 = al_s[sA * 3 + 1] + ald1; e1 = e1 > 0.f ? e1 : NEG_SLOPE * e1;
            float e2 = al_s[sA * 3 + 2] + ald2; e2 = e2 > 0.f ? e2 : NEG_SLOPE * e2;
            wA0 = __expf(e0); wA1 = __expf(e1); wA2 = __expf(e2);
        }
        if (vB) {
            float e0 = al_s[sB * 3 + 0] + ald0; e0 = e0 > 0.f ? e0 : NEG_SLOPE * e0;
            float e1 = al_s[sB * 3 + 1] + ald1; e1 = e1 > 0.f ? e1 : NEG_SLOPE * e1;
            float e2 = al_s[sB * 3 + 2] + ald2; e2 = e2 > 0.f ? e2 : NEG_SLOPE * e2;
            wB0 = __expf(e0); wB1 = __expf(e1); wB2 = __expf(e2);
        }
        sw0 += wA0 + wB0; sw1 += wA1 + wB1; sw2 += wA2 + wB2;
        half8 xvA = *(const half8*)(xh + (size_t)sA * 128 + chunk * 8);
        half8 xvB = *(const half8*)(xh + (size_t)sB * 128 + chunk * 8);
#pragma unroll
        for (int k = 0; k < 8; ++k) {
            float fA = (float)xvA[k], fB = (float)xvB[k];
            acc0[k] = fmaf(wA0, fA, acc0[k]); acc0[k] = fmaf(wB0, fB, acc0[k]);
            acc1[k] = fmaf(wA1, fA, acc1[k]); acc1[k] = fmaf(wB1, fB, acc1[k]);
            acc2[k] = fmaf(wA2, fA, acc2[k]); acc2[k] = fmaf(wB2, fB, acc2[k]);
        }
    }
#pragma unroll
    for (int k = 0; k < 8; ++k) {
        acc0[k] += __shfl_xor(acc0[k], 16); acc0[k] += __shfl_xor(acc0[k], 32);
        acc1[k] += __shfl_xor(acc1[k], 16); acc1[k] += __shfl_xor(acc1[k], 32);
        acc2[k] += __shfl_xor(acc2[k], 16); acc2[k] += __shfl_xor(acc2[k], 32);
    }
    sw0 += __shfl_xor(sw0, 16); sw0 += __shfl_xor(sw0, 32);
    sw1 += __shfl_xor(sw1, 16); sw1 += __shfl_xor(sw1, 32);
    sw2 += __shfl_xor(sw2, 16); sw2 += __shfl_xor(sw2, 32);

    if (lane < 16) {
        float i0 = 1.f / sw0, i1 = 1.f / sw1, i2 = 1.f / sw2;
        _Float16* op = xagg + (size_t)wid * 384 + chunk * 8;
        half8 o0, o1, o2;
#pragma unroll
        for (int k = 0; k < 8; ++k) {
            o0[k] = (_Float16)(acc0[k] * i0);
            o1[k] = (_Float16)(acc1[k] * i1);
            o2[k] = (_Float16)(acc2[k] * i2);
        }
        *(half8*)(op + 0)   = o0;
        *(half8*)(op + 128) = o1;
        *(half8*)(op + 256) = o2;
    }
}

// ------------------------------------------------------------ fp16 MFMA GEMM
// GAT=true (layer 1): A = xagg[M][3][128], head = col/256; epilogue bias+ReLU,
//   writes x2h fp16 + accumulates layer-2 logits via atomics.
// GAT=false (layer 2): C written as 3 SPLIT TABLES of 128 cols each
//   (C[(col>>7)*M*128 + row*128 + (col&127)]) so the layer-2 gather's working
//   set per table is 5MB ~ L2-resident.
__device__ __forceinline__ void gload_lds16(const _Float16* g, _Float16* l) {
    __builtin_amdgcn_global_load_lds((const __attribute__((address_space(1))) void*)g,
                                     (__attribute__((address_space(3))) void*)l,
                                     16, 0, 0);
}

template <typename OutT, bool GAT>
__global__ __launch_bounds__(256) void k_hgemm(const _Float16* __restrict__ A,
                                               const _Float16* __restrict__ Bt,
                                               const float* __restrict__ bias,
                                               const float* __restrict__ vs2,
                                               const float* __restrict__ vd2,
                                               float* __restrict__ alS2,
                                               float* __restrict__ alD2,
                                               OutT* __restrict__ C,
                                               int M, int N, int K) {
    __shared__ _Float16 lds[2 * 8192];
    int t = threadIdx.x;
    int lane = t & 63, w = t >> 6;
    int wr = w >> 1, wc = w & 1;
    int lrow = lane & 15, lko = lane >> 4;
    int row0 = blockIdx.y * 128, col0 = blockIdx.x * 128;

    int sr = t & 127;
    int sko = t >> 7;
    int agr = row0 + sr; if (agr >= M) agr = M - 1;
    const _Float16* aRow;
    if constexpr (GAT) {
        int head = col0 >> 8;
        aRow = A + (size_t)agr * 384 + head * 128;
    } else {
        aRow = A + (size_t)agr * K;
    }
    const _Float16* bRow = Bt + (size_t)(col0 + sr) * K;

    floatx4 acc[4][4] = {};

    int nk = K >> 5;
#pragma unroll
    for (int s = 0; s < 2; ++s) {
        int ko = s * 2 + sko;
        gload_lds16(aRow + ko * 8, lds + s * 2048 + t * 8);
        gload_lds16(bRow + ko * 8, lds + 4096 + s * 2048 + t * 8);
    }
    __syncthreads();

    for (int ks = 0; ks < nk; ++ks) {
        int buf = ks & 1;
        if (ks + 1 < nk) {
            int kt = (ks + 1) << 5;
            _Float16* dstb = lds + (buf ^ 1) * 8192;
#pragma unroll
            for (int s = 0; s < 2; ++s) {
                int ko = s * 2 + sko;
                gload_lds16(aRow + kt + ko * 8, dstb + s * 2048 + t * 8);
                gload_lds16(bRow + kt + ko * 8, dstb + 4096 + s * 2048 + t * 8);
            }
        }
        const _Float16* base = lds + buf * 8192 + lko * 1024;
        half8 af[4], bf[4];
#pragma unroll
        for (int mi = 0; mi < 4; ++mi)
            af[mi] = *(const half8*)(base + (wr * 64 + mi * 16 + lrow) * 8);
#pragma unroll
        for (int ni = 0; ni < 4; ++ni)
            bf[ni] = *(const half8*)(base + 4096 + (wc * 64 + ni * 16 + lrow) * 8);
#pragma unroll
        for (int mi = 0; mi < 4; ++mi)
#pragma unroll
            for (int ni = 0; ni < 4; ++ni)
                acc[mi][ni] = __builtin_amdgcn_mfma_f32_16x16x32_f16(
                    af[mi], bf[ni], acc[mi][ni], 0, 0, 0);
        __syncthreads();
    }

    size_t tblstride = (size_t)M * 128;
#pragma unroll
    for (int mi = 0; mi < 4; ++mi) {
#pragma unroll
        for (int j = 0; j < 4; ++j) {
            int row = row0 + wr * 64 + mi * 16 + lko * 4 + j;
            float ps = 0.f, pd = 0.f;
#pragma unroll
            for (int ni = 0; ni < 4; ++ni) {
                int col = col0 + wc * 64 + ni * 16 + lrow;
                float v = acc[mi][ni][j];
                if constexpr (GAT) {
                    v += bias[col]; v = v > 0.f ? v : 0.f;
                    ps = fmaf(v, vs2[col], ps);
                    pd = fmaf(v, vd2[col], pd);
                    if (row < M) C[(size_t)row * N + col] = (OutT)v;
                } else {
                    if (row < M)
                        C[(size_t)(col >> 7) * tblstride + (size_t)row * 128 + (col & 127)] = (OutT)v;
                }
            }
            if constexpr (GAT) {
                if (row >= M) { ps = 0.f; pd = 0.f; }
#pragma unroll
                for (int off = 1; off < 16; off <<= 1) {
                    ps += __shfl_xor(ps, off);
                    pd += __shfl_xor(pd, off);
                }
                if (lrow == 0 && row < M) {
                    atomicAdd(&alS2[row], ps);
                    atomicAdd(&alD2[row], pd);
                }
            }
        }
    }
}

// ------------- layer-2 gather-agg v3: 2 waves/node, 3 L2-sized table passes
// h2 split as T[t][node][128] fp16 (5MB each). Edge (src,weight) loaded once
// per 64-edge group into registers; per third t: one half2 gather per lane
// per edge (64 lanes cover the 128-ch row).
__global__ __launch_bounds__(256) void k_aggw2(const _Float16* __restrict__ h2s,
                                               const float* __restrict__ al_s,
                                               const float* __restrict__ al_d,
                                               const int* __restrict__ rowptr,
                                               const int* __restrict__ csr_src,
                                               const float* __restrict__ bias,
                                               float* __restrict__ out, int n) {
    int wv = threadIdx.x >> 6;
    int lane = threadIdx.x & 63;
    int node = blockIdx.x * 2 + (wv >> 1);
    int half = wv & 1;
    int ns = wv >> 1;

    __shared__ float s_acc[2][64][6];
    __shared__ float s_sw[2];

    int beg = rowptr[node], end = rowptr[node + 1];
    float ald = al_d[node];
    size_t tbl = (size_t)n * 128;

    float acc[3][2] = {};
    float swsum = 0.f;

    for (int base = beg + half; base < end; base += 128) {
        int myi = base + 2 * lane;
        bool valid = myi < end;
        int sl = valid ? csr_src[myi] : 0;
        float wl = 0.f;
        if (valid) {
            float e = al_s[sl] + ald;
            e = e > 0.f ? e : NEG_SLOPE * e;
            wl = __expf(e);
        }
        swsum += wl;
        int cnt = min(64, (end - base + 1) >> 1);
#pragma unroll
        for (int t = 0; t < 3; ++t) {
            const _Float16* T = h2s + (size_t)t * tbl;
            int j = 0;
            for (; j + 4 <= cnt; j += 4) {
                int ss0 = __shfl(sl, j + 0), ss1 = __shfl(sl, j + 1);
                int ss2 = __shfl(sl, j + 2), ss3 = __shfl(sl, j + 3);
                float w0 = __shfl(wl, j + 0), w1 = __shfl(wl, j + 1);
                float w2 = __shfl(wl, j + 2), w3 = __shfl(wl, j + 3);
                half2v v0 = *(const half2v*)(T + (size_t)ss0 * 128 + lane * 2);
                half2v v1 = *(const half2v*)(T + (size_t)ss1 * 128 + lane * 2);
                half2v v2 = *(const half2v*)(T + (size_t)ss2 * 128 + lane * 2);
                half2v v3 = *(const half2v*)(T + (size_t)ss3 * 128 + lane * 2);
                acc[t][0] = fmaf(w0, (float)v0[0], acc[t][0]);
                acc[t][1] = fmaf(w0, (float)v0[1], acc[t][1]);
                acc[t][0] = fmaf(w1, (float)v1[0], acc[t][0]);
                acc[t][1] = fmaf(w1, (float)v1[1], acc[t][1]);
                acc[t][0] = fmaf(w2, (float)v2[0], acc[t][0]);
                acc[t][1] = fmaf(w2, (float)v2[1], acc[t][1]);
                acc[t][0] = fmaf(w3, (float)v3[0], acc[t][0]);
                acc[t][1] = fmaf(w3, (float)v3[1], acc[t][1]);
            }
            for (; j < cnt; ++j) {
                int s = __shfl(sl, j);
                float ww = __shfl(wl, j);
                half2v v = *(const half2v*)(T + (size_t)s * 128 + lane * 2);
                acc[t][0] = fmaf(ww, (float)v[0], acc[t][0]);
                acc[t][1] = fmaf(ww, (float)v[1], acc[t][1]);
            }
        }
    }

#pragma unroll
    for (int off = 32; off; off >>= 1) swsum += __shfl_xor(swsum, off);

    if (half == 1) {
#pragma unroll
        for (int t = 0; t < 3; ++t) {
            s_acc[ns][lane][t * 2 + 0] = acc[t][0];
            s_acc[ns][lane][t * 2 + 1] = acc[t][1];
        }
        if (lane == 0) s_sw[ns] = swsum;
    }
    __syncthreads();
    if (half == 1) return;

    float inv = 1.f / (swsum + s_sw[ns]);
    size_t obase = (size_t)node * 384;
#pragma unroll
    for (int t = 0; t < 3; ++t) {
        int ch = t * 128 + lane * 2;
        float a0 = (acc[t][0] + s_acc[ns][lane][t * 2 + 0]) * inv + bias[ch];
        float a1 = (acc[t][1] + s_acc[ns][lane][t * 2 + 1]) * inv + bias[ch + 1];
        floatx2 o;
        o[0] = a0 > 0.f ? a0 : 0.f;
        o[1] = a1 > 0.f ? a1 : 0.f;
        *(floatx2*)(out + obase + ch) = o;
    }
}

// ---------------------------------------------------------------------- host
extern "C" void kernel_launch(void* const* d_in, const int* in_sizes, int n_in,
                              void* d_out, int out_size, void* d_ws, size_t ws_size,
                              hipStream_t stream) {
    const float* x   = (const float*)d_in[0];
    const int*   ei  = (const int*)d_in[1];
    const float* W1  = (const float*)d_in[2];
    const float* as1 = (const float*)d_in[3];
    const float* ad1 = (const float*)d_in[4];
    const float* b1  = (const float*)d_in[5];
    const float* W2  = (const float*)d_in[6];
    const float* as2 = (const float*)d_in[7];
    const float* ad2 = (const float*)d_in[8];
    const float* b2  = (const float*)d_in[9];
    float* out = (float*)d_out;

    const int N  = in_sizes[0] / 128;   // 20000
    const int E  = in_sizes[1] / 2;     // 320000
    const int ET = E + N;
    const int NB = (N + 255) / 256;
    const int* src = ei;
    const int* dst = ei + E;

    char* ws = (char*)d_ws;
    size_t off = 0;
    auto alloc = [&](size_t bytes) {
        void* p = ws + off;
        off = (off + bytes + 255) & ~(size_t)255;
        return p;
    };
    _Float16* xh    = (_Float16*)alloc((size_t)N * 128 * 2);
    _Float16* xagg  = (_Float16*)alloc((size_t)N * 384 * 2);
    _Float16* x2h   = (_Float16*)alloc((size_t)N * 768 * 2);
    _Float16* h2s   = (_Float16*)alloc((size_t)N * 384 * 2);  // 3 split tables
    _Float16* w1t   = (_Float16*)alloc((size_t)768 * 128 * 2);
    _Float16* w2t   = (_Float16*)alloc((size_t)384 * 768 * 2);
    float* vs1  = (float*)alloc(384 * 4);
    float* vd1  = (float*)alloc(384 * 4);
    float* vs2  = (float*)alloc(768 * 4);
    float* vd2  = (float*)alloc(768 * 4);
    float* alS1 = (float*)alloc((size_t)N * 3 * 4);
    float* alD1 = (float*)alloc((size_t)N * 3 * 4);
    // zero-initialized region: deg | alS2 | alD2 (one memset)
    int*   deg  = (int*)alloc((size_t)N * 4);
    float* alS2 = (float*)alloc((size_t)N * 4);
    float* alD2 = (float*)alloc((size_t)N * 4);
    int* rowptr = (int*)alloc((size_t)(N + 1) * 4);
    int* cursor = (int*)alloc((size_t)N * 4);
    int* bsum   = (int*)alloc(256 * 4);
    int* csrs   = (int*)alloc((size_t)ET * 4);

    hipMemsetAsync(deg, 0, (size_t)((char*)rowptr - (char*)deg), stream);

    // CSR by destination (shared by both layers)
    k_hist<<<(ET + 255) / 256, 256, 0, stream>>>(dst, E, N, deg);
    k_scan1<<<NB, 256, 0, stream>>>(deg, bsum, N);
    k_scan3<<<NB, 256, 0, stream>>>(deg, bsum, NB, rowptr, cursor, N);
    k_scatter<<<(ET + 255) / 256, 256, 0, stream>>>(src, dst, E, N, cursor, csrs);

    // fused weight prep
    k_wprep<<<1541, 256, 0, stream>>>(W1, W2, as1, ad1, as2, ad2,
                                      w1t, w2t, vs1, vd1, vs2, vd2);

    // layer 1
    k_prep1<<<(N + 3) / 4, 256, 0, stream>>>(x, xh, vs1, vd1, alS1, alD1, N);
    k_aggx<<<(N + 3) / 4, 256, 0, stream>>>(xh, alS1, alD1, rowptr, csrs, xagg, N);
    dim3 g1(768 / 128, (N + 127) / 128);
    k_hgemm<_Float16, true><<<g1, 256, 0, stream>>>(xagg, w1t, b1, vs2, vd2,
                                                    alS2, alD2, x2h, N, 768, 128);

    // layer 2 (GEMM writes 3 split tables; gather makes 3 L2-resident passes)
    dim3 g2(384 / 128, (N + 127) / 128);
    k_hgemm<_Float16, false><<<g2, 256, 0, stream>>>(x2h, w2t, nullptr, nullptr,
                                                     nullptr, nullptr, nullptr,
                                                     h2s, N, 384, 768);
    k_aggw2<<<N / 2, 256, 0, stream>>>(h2s, alS2, alD2, rowptr, csrs, b2, out, N);
}

// Round 11
// 213.747 us; speedup vs baseline: 1.0038x; 1.0038x over previous
//
#include <hip/hip_runtime.h>
#include <hip/hip_bf16.h>

#define NEG_SLOPE 0.2f

typedef _Float16 half8 __attribute__((ext_vector_type(8)));
typedef _Float16 half4v __attribute__((ext_vector_type(4)));
typedef _Float16 half2v __attribute__((ext_vector_type(2)));
typedef float floatx4 __attribute__((ext_vector_type(4)));
typedef float floatx2 __attribute__((ext_vector_type(2)));

// ---------------------------------------------------------------- CSR build
__global__ void k_hist(const int* __restrict__ dst, int E, int n, int* __restrict__ deg) {
    int e = blockIdx.x * blockDim.x + threadIdx.x;
    int ET = E + n;
    if (e >= ET) return;
    int d = (e < E) ? dst[e] : (e - E);   // self-loops appended
    atomicAdd(&deg[d], 1);
}

// phase 1: per-block sums (coalesced)
__global__ void k_scan1(const int* __restrict__ deg, int* __restrict__ bsum, int n) {
    __shared__ int red[256];
    int t = threadIdx.x, b = blockIdx.x;
    int i = b * 256 + t;
    red[t] = (i < n) ? deg[i] : 0;
    __syncthreads();
    for (int off = 128; off; off >>= 1) {
        if (t < off) red[t] += red[t + off];
        __syncthreads();
    }
    if (t == 0) bsum[b] = red[0];
}

// phase 2+3 fused: every block prefixes the (<=256) block sums itself, then
// does its local inclusive scan + offset -> rowptr/cursor.
__global__ void k_scan3(const int* __restrict__ deg, const int* __restrict__ bsum,
                        int nb, int* __restrict__ rowptr, int* __restrict__ cursor,
                        int n) {
    __shared__ int s[256];
    int t = threadIdx.x, b = blockIdx.x;
    s[t] = (t < nb) ? bsum[t] : 0;
    __syncthreads();
    for (int off = 1; off < 256; off <<= 1) {
        int v = (t >= off) ? s[t - off] : 0;
        __syncthreads();
        s[t] += v;
        __syncthreads();
    }
    int base = (b == 0) ? 0 : s[b - 1];
    __syncthreads();
    int i = b * 256 + t;
    int v = (i < n) ? deg[i] : 0;
    s[t] = v;
    __syncthreads();
    for (int off = 1; off < 256; off <<= 1) {
        int u = (t >= off) ? s[t - off] : 0;
        __syncthreads();
        s[t] += u;
        __syncthreads();
    }
    int incl = s[t];
    if (i < n) {
        rowptr[i] = base + incl - v;
        cursor[i] = base + incl - v;
        if (i == n - 1) rowptr[n] = base + incl;
    }
}

__global__ void k_scatter(const int* __restrict__ src, const int* __restrict__ dst,
                          int E, int n, int* __restrict__ cursor,
                          int* __restrict__ csr_src) {
    int e = blockIdx.x * blockDim.x + threadIdx.x;
    int ET = E + n;
    if (e >= ET) return;
    int s = (e < E) ? src[e] : (e - E);
    int d = (e < E) ? dst[e] : (e - E);
    int pos = atomicAdd(&cursor[d], 1);
    csr_src[pos] = s;
}

// --------------------- fused weight prep: W1t, W2t transposes + vs/vd vectors
__global__ void k_wprep(const float* __restrict__ W1, const float* __restrict__ W2,
                        const float* __restrict__ as1, const float* __restrict__ ad1,
                        const float* __restrict__ as2, const float* __restrict__ ad2,
                        _Float16* __restrict__ w1t, _Float16* __restrict__ w2t,
                        float* __restrict__ vs1, float* __restrict__ vd1,
                        float* __restrict__ vs2, float* __restrict__ vd2) {
    int b = blockIdx.x;
    if (b < 384) {                       // W1[128][768] -> w1t[768][128]
        int i = b * 256 + threadIdx.x;
        int c = i / 128, r = i % 128;
        w1t[i] = (_Float16)W1[(size_t)r * 768 + c];
    } else if (b < 1536) {               // W2[768][384] -> w2t[384][768]
        int i = (b - 384) * 256 + threadIdx.x;
        int c = i / 768, r = i % 768;
        w2t[i] = (_Float16)W2[(size_t)r * 384 + c];
    } else if (b < 1538) {               // vs1/vd1 (384 outputs)
        int t = (b - 1536) * 256 + threadIdx.x;
        if (t < 384) {
            int h = t >> 7, k = t & 127;
            const float* wr = W1 + (size_t)k * 768 + h * 256;
            const float* ar = as1 + h * 256;
            const float* dr = ad1 + h * 256;
            float s = 0.f, d = 0.f;
            for (int c = 0; c < 256; ++c) { float wv = wr[c]; s += wv * ar[c]; d += wv * dr[c]; }
            vs1[t] = s; vd1[t] = d;
        }
    } else {                             // vs2/vd2 (768 outputs)
        int t = (b - 1538) * 256 + threadIdx.x;
        if (t < 768) {
            const float* wr = W2 + (size_t)t * 384;
            float s = 0.f, d = 0.f;
            for (int c = 0; c < 384; ++c) { float wv = wr[c]; s += wv * as2[c]; d += wv * ad2[c]; }
            vs2[t] = s; vd2[t] = d;
        }
    }
}

// -------------------------- fused x fp32->fp16 + layer-1 logits (one pass)
__global__ __launch_bounds__(256) void k_prep1(const float* __restrict__ x,
        _Float16* __restrict__ xh, const float* __restrict__ vs,
        const float* __restrict__ vd, float* __restrict__ al_s,
        float* __restrict__ al_d, int n) {
    int wid = (blockIdx.x * blockDim.x + threadIdx.x) >> 6;
    int lane = threadIdx.x & 63;
    if (wid >= n) return;
    float2 f = *(const float2*)(x + (size_t)wid * 128 + lane * 2);
    half2v hv; hv[0] = (_Float16)f.x; hv[1] = (_Float16)f.y;
    *(half2v*)(xh + (size_t)wid * 128 + lane * 2) = hv;
    float aS[3], aD[3];
#pragma unroll
    for (int hh = 0; hh < 3; ++hh) {
        floatx2 v = *(const floatx2*)(vs + hh * 128 + lane * 2);
        floatx2 d = *(const floatx2*)(vd + hh * 128 + lane * 2);
        aS[hh] = f.x * v[0] + f.y * v[1];
        aD[hh] = f.x * d[0] + f.y * d[1];
    }
#pragma unroll
    for (int hh = 0; hh < 3; ++hh)
#pragma unroll
        for (int off = 32; off; off >>= 1) {
            aS[hh] += __shfl_xor(aS[hh], off);
            aD[hh] += __shfl_xor(aD[hh], off);
        }
    if (lane == 0) {
#pragma unroll
        for (int hh = 0; hh < 3; ++hh) { al_s[wid * 3 + hh] = aS[hh]; al_d[wid * 3 + hh] = aD[hh]; }
    }
}

// ---------------------- layer-1 aggregation in INPUT space, inline edge exp
// No-max softmax: logits O(+-3) by Glorot arithmetic -> exp safe; alpha ratio
// identical (validated R6-R10, absmax 2e-3).
__global__ __launch_bounds__(256) void k_aggx(const _Float16* __restrict__ xh,
                                              const float* __restrict__ al_s,
                                              const float* __restrict__ al_d,
                                              const int* __restrict__ rowptr,
                                              const int* __restrict__ csr_src,
                                              _Float16* __restrict__ xagg,
                                              int n) {
    int wid = (blockIdx.x * blockDim.x + threadIdx.x) >> 6;
    int lane = threadIdx.x & 63;
    if (wid >= n) return;
    int beg = rowptr[wid], end = rowptr[wid + 1];
    int slot = lane >> 4;     // 0..3  (edge within group)
    int chunk = lane & 15;    // channel chunk

    float ald0 = al_d[wid * 3 + 0], ald1 = al_d[wid * 3 + 1], ald2 = al_d[wid * 3 + 2];

    float acc0[8] = {}, acc1[8] = {}, acc2[8] = {};
    float sw0 = 0.f, sw1 = 0.f, sw2 = 0.f;

    for (int base = beg; base < end; base += 8) {
        int eA = base + slot, eB = base + 4 + slot;
        bool vA = eA < end, vB = eB < end;
        int sA = vA ? csr_src[eA] : 0;
        int sB = vB ? csr_src[eB] : 0;
        float wA0 = 0.f, wA1 = 0.f, wA2 = 0.f, wB0 = 0.f, wB1 = 0.f, wB2 = 0.f;
        if (vA) {
            float e0 = al_s[sA * 3 + 0] + ald0; e0 = e0 > 0.f ? e0 : NEG_SLOPE * e0;
            float e1 = al_s[sA * 3 + 1] + ald1; e1 = e1 > 0.f ? e1 : NEG_SLOPE * e1;
            float e2 = al_s[sA * 3 + 2] + ald2; e2 = e2 > 0.f ? e2 : NEG_SLOPE * e2;
            wA0 = __expf(e0); wA1 = __expf(e1); wA2 = __expf(e2);
        }
        if (vB) {
            float e0 = al_s[sB * 3 + 0] + ald0; e0 = e0 > 0.f ? e0 : NEG_SLOPE * e0;
            float e1 = al_s[sB * 3 + 1] + ald1; e1 = e1 > 0.f ? e1 : NEG_SLOPE * e1;
            float e2 = al_s[sB * 3 + 2] + ald2; e2 = e2 > 0.f ? e2 : NEG_SLOPE * e2;
            wB0 = __expf(e0); wB1 = __expf(e1); wB2 = __expf(e2);
        }
        sw0 += wA0 + wB0; sw1 += wA1 + wB1; sw2 += wA2 + wB2;
        half8 xvA = *(const half8*)(xh + (size_t)sA * 128 + chunk * 8);
        half8 xvB = *(const half8*)(xh + (size_t)sB * 128 + chunk * 8);
#pragma unroll
        for (int k = 0; k < 8; ++k) {
            float fA = (float)xvA[k], fB = (float)xvB[k];
            acc0[k] = fmaf(wA0, fA, acc0[k]); acc0[k] = fmaf(wB0, fB, acc0[k]);
            acc1[k] = fmaf(wA1, fA, acc1[k]); acc1[k] = fmaf(wB1, fB, acc1[k]);
            acc2[k] = fmaf(wA2, fA, acc2[k]); acc2[k] = fmaf(wB2, fB, acc2[k]);
        }
    }
#pragma unroll
    for (int k = 0; k < 8; ++k) {
        acc0[k] += __shfl_xor(acc0[k], 16); acc0[k] += __shfl_xor(acc0[k], 32);
        acc1[k] += __shfl_xor(acc1[k], 16); acc1[k] += __shfl_xor(acc1[k], 32);
        acc2[k] += __shfl_xor(acc2[k], 16); acc2[k] += __shfl_xor(acc2[k], 32);
    }
    sw0 += __shfl_xor(sw0, 16); sw0 += __shfl_xor(sw0, 32);
    sw1 += __shfl_xor(sw1, 16); sw1 += __shfl_xor(sw1, 32);
    sw2 += __shfl_xor(sw2, 16); sw2 += __shfl_xor(sw2, 32);

    if (lane < 16) {
        float i0 = 1.f / sw0, i1 = 1.f / sw1, i2 = 1.f / sw2;
        _Float16* op = xagg + (size_t)wid * 384 + chunk * 8;
        half8 o0, o1, o2;
#pragma unroll
        for (int k = 0; k < 8; ++k) {
            o0[k] = (_Float16)(acc0[k] * i0);
            o1[k] = (_Float16)(acc1[k] * i1);
            o2[k] = (_Float16)(acc2[k] * i2);
        }
        *(half8*)(op + 0)   = o0;
        *(half8*)(op + 128) = o1;
        *(half8*)(op + 256) = o2;
    }
}

// ------------------------------------------------------------ fp16 MFMA GEMM
// GAT=true (layer 1): A = xagg[M][3][128], head = col/256; epilogue bias+ReLU,
//   writes x2h fp16 + accumulates layer-2 logits via atomics.
// GAT=false (layer 2): plain C = A @ Bt^T, row-major fp16 out.
__device__ __forceinline__ void gload_lds16(const _Float16* g, _Float16* l) {
    __builtin_amdgcn_global_load_lds((const __attribute__((address_space(1))) void*)g,
                                     (__attribute__((address_space(3))) void*)l,
                                     16, 0, 0);
}

template <typename OutT, bool GAT>
__global__ __launch_bounds__(256) void k_hgemm(const _Float16* __restrict__ A,
                                               const _Float16* __restrict__ Bt,
                                               const float* __restrict__ bias,
                                               const float* __restrict__ vs2,
                                               const float* __restrict__ vd2,
                                               float* __restrict__ alS2,
                                               float* __restrict__ alD2,
                                               OutT* __restrict__ C,
                                               int M, int N, int K) {
    __shared__ _Float16 lds[2 * 8192];
    int t = threadIdx.x;
    int lane = t & 63, w = t >> 6;
    int wr = w >> 1, wc = w & 1;
    int lrow = lane & 15, lko = lane >> 4;
    int row0 = blockIdx.y * 128, col0 = blockIdx.x * 128;

    int sr = t & 127;
    int sko = t >> 7;
    int agr = row0 + sr; if (agr >= M) agr = M - 1;
    const _Float16* aRow;
    if constexpr (GAT) {
        int head = col0 >> 8;
        aRow = A + (size_t)agr * 384 + head * 128;
    } else {
        aRow = A + (size_t)agr * K;
    }
    const _Float16* bRow = Bt + (size_t)(col0 + sr) * K;

    floatx4 acc[4][4] = {};

    int nk = K >> 5;
#pragma unroll
    for (int s = 0; s < 2; ++s) {
        int ko = s * 2 + sko;
        gload_lds16(aRow + ko * 8, lds + s * 2048 + t * 8);
        gload_lds16(bRow + ko * 8, lds + 4096 + s * 2048 + t * 8);
    }
    __syncthreads();

    for (int ks = 0; ks < nk; ++ks) {
        int buf = ks & 1;
        if (ks + 1 < nk) {
            int kt = (ks + 1) << 5;
            _Float16* dstb = lds + (buf ^ 1) * 8192;
#pragma unroll
            for (int s = 0; s < 2; ++s) {
                int ko = s * 2 + sko;
                gload_lds16(aRow + kt + ko * 8, dstb + s * 2048 + t * 8);
                gload_lds16(bRow + kt + ko * 8, dstb + 4096 + s * 2048 + t * 8);
            }
        }
        const _Float16* base = lds + buf * 8192 + lko * 1024;
        half8 af[4], bf[4];
#pragma unroll
        for (int mi = 0; mi < 4; ++mi)
            af[mi] = *(const half8*)(base + (wr * 64 + mi * 16 + lrow) * 8);
#pragma unroll
        for (int ni = 0; ni < 4; ++ni)
            bf[ni] = *(const half8*)(base + 4096 + (wc * 64 + ni * 16 + lrow) * 8);
#pragma unroll
        for (int mi = 0; mi < 4; ++mi)
#pragma unroll
            for (int ni = 0; ni < 4; ++ni)
                acc[mi][ni] = __builtin_amdgcn_mfma_f32_16x16x32_f16(
                    af[mi], bf[ni], acc[mi][ni], 0, 0, 0);
        __syncthreads();
    }

#pragma unroll
    for (int mi = 0; mi < 4; ++mi) {
#pragma unroll
        for (int j = 0; j < 4; ++j) {
            int row = row0 + wr * 64 + mi * 16 + lko * 4 + j;
            float ps = 0.f, pd = 0.f;
#pragma unroll
            for (int ni = 0; ni < 4; ++ni) {
                int col = col0 + wc * 64 + ni * 16 + lrow;
                float v = acc[mi][ni][j];
                if constexpr (GAT) {
                    v += bias[col]; v = v > 0.f ? v : 0.f;
                    ps = fmaf(v, vs2[col], ps);
                    pd = fmaf(v, vd2[col], pd);
                }
                if (row < M) C[(size_t)row * N + col] = (OutT)v;
            }
            if constexpr (GAT) {
                if (row >= M) { ps = 0.f; pd = 0.f; }
#pragma unroll
                for (int off = 1; off < 16; off <<= 1) {
                    ps += __shfl_xor(ps, off);
                    pd += __shfl_xor(pd, off);
                }
                if (lrow == 0 && row < M) {
                    atomicAdd(&alS2[row], ps);
                    atomicAdd(&alD2[row], pd);
                }
            }
        }
    }
}

// ---------- layer-2 gather-agg v4: ONE BLOCK (4 waves) PER NODE, LDS combine
// Wave wv handles edges {beg + 4j + wv}; per edge: half4+half2 gather (12B/
// lane, 2 VMEM covering all 384 ch). Serial chain per wave ~deg/4 edges.
__global__ __launch_bounds__(256) void k_aggw2(const _Float16* __restrict__ h,
                                               const float* __restrict__ al_s,
                                               const float* __restrict__ al_d,
                                               const int* __restrict__ rowptr,
                                               const int* __restrict__ csr_src,
                                               const float* __restrict__ bias,
                                               float* __restrict__ out, int n) {
    constexpr int HC = 384;
    int wv = threadIdx.x >> 6;          // 0..3
    int lane = threadIdx.x & 63;
    int node = blockIdx.x;

    __shared__ float s_acc[3][64][6];
    __shared__ float s_sw[4];

    int beg = rowptr[node], end = rowptr[node + 1];
    float ald = al_d[node];

    float accA[4] = {}, accB[2] = {};
    float swsum = 0.f;

    for (int base = beg; base < end; base += 256) {
        int myi = base + 4 * lane + wv;
        bool valid = myi < end;
        int sl = valid ? csr_src[myi] : 0;
        float wl = 0.f;
        if (valid) {
            float e = al_s[sl] + ald;
            e = e > 0.f ? e : NEG_SLOPE * e;
            wl = __expf(e);
        }
        swsum += wl;
        int rem = end - base - wv;
        int cnt = rem > 0 ? min(64, (rem + 3) >> 2) : 0;
        int j = 0;
        for (; j + 4 <= cnt; j += 4) {
            int ss0 = __shfl(sl, j + 0), ss1 = __shfl(sl, j + 1);
            int ss2 = __shfl(sl, j + 2), ss3 = __shfl(sl, j + 3);
            float w0 = __shfl(wl, j + 0), w1 = __shfl(wl, j + 1);
            float w2 = __shfl(wl, j + 2), w3 = __shfl(wl, j + 3);
            const _Float16* r0 = h + (size_t)ss0 * HC;
            const _Float16* r1 = h + (size_t)ss1 * HC;
            const _Float16* r2 = h + (size_t)ss2 * HC;
            const _Float16* r3 = h + (size_t)ss3 * HC;
            half4v va0 = *(const half4v*)(r0 + lane * 4);
            half4v va1 = *(const half4v*)(r1 + lane * 4);
            half4v va2 = *(const half4v*)(r2 + lane * 4);
            half4v va3 = *(const half4v*)(r3 + lane * 4);
            half2v vb0 = *(const half2v*)(r0 + 256 + lane * 2);
            half2v vb1 = *(const half2v*)(r1 + 256 + lane * 2);
            half2v vb2 = *(const half2v*)(r2 + 256 + lane * 2);
            half2v vb3 = *(const half2v*)(r3 + 256 + lane * 2);
#pragma unroll
            for (int k = 0; k < 4; ++k) {
                accA[k] = fmaf(w0, (float)va0[k], accA[k]);
                accA[k] = fmaf(w1, (float)va1[k], accA[k]);
                accA[k] = fmaf(w2, (float)va2[k], accA[k]);
                accA[k] = fmaf(w3, (float)va3[k], accA[k]);
            }
#pragma unroll
            for (int k = 0; k < 2; ++k) {
                accB[k] = fmaf(w0, (float)vb0[k], accB[k]);
                accB[k] = fmaf(w1, (float)vb1[k], accB[k]);
                accB[k] = fmaf(w2, (float)vb2[k], accB[k]);
                accB[k] = fmaf(w3, (float)vb3[k], accB[k]);
            }
        }
        for (; j < cnt; ++j) {
            int s = __shfl(sl, j);
            float ww = __shfl(wl, j);
            const _Float16* row = h + (size_t)s * HC;
            half4v va = *(const half4v*)(row + lane * 4);
            half2v vb = *(const half2v*)(row + 256 + lane * 2);
#pragma unroll
            for (int k = 0; k < 4; ++k) accA[k] = fmaf(ww, (float)va[k], accA[k]);
#pragma unroll
            for (int k = 0; k < 2; ++k) accB[k] = fmaf(ww, (float)vb[k], accB[k]);
        }
    }

#pragma unroll
    for (int off = 32; off; off >>= 1) swsum += __shfl_xor(swsum, off);

    if (wv > 0) {
#pragma unroll
        for (int k = 0; k < 4; ++k) s_acc[wv - 1][lane][k] = accA[k];
#pragma unroll
        for (int k = 0; k < 2; ++k) s_acc[wv - 1][lane][4 + k] = accB[k];
    }
    if (lane == 0) s_sw[wv] = swsum;
    __syncthreads();
    if (wv != 0) return;

#pragma unroll
    for (int k = 0; k < 4; ++k)
        accA[k] += s_acc[0][lane][k] + s_acc[1][lane][k] + s_acc[2][lane][k];
#pragma unroll
    for (int k = 0; k < 2; ++k)
        accB[k] += s_acc[0][lane][4 + k] + s_acc[1][lane][4 + k] + s_acc[2][lane][4 + k];
    float inv = 1.f / (s_sw[0] + s_sw[1] + s_sw[2] + s_sw[3]);

    size_t obase = (size_t)node * HC;
    int cA0 = lane * 4, cB0 = 256 + lane * 2;
    float4 oa;
    float t0 = accA[0] * inv + bias[cA0 + 0]; oa.x = t0 > 0.f ? t0 : 0.f;
    float t1 = accA[1] * inv + bias[cA0 + 1]; oa.y = t1 > 0.f ? t1 : 0.f;
    float t2 = accA[2] * inv + bias[cA0 + 2]; oa.z = t2 > 0.f ? t2 : 0.f;
    float t3 = accA[3] * inv + bias[cA0 + 3]; oa.w = t3 > 0.f ? t3 : 0.f;
    *(float4*)(out + obase + cA0) = oa;
    floatx2 ob;
    float u0 = accB[0] * inv + bias[cB0 + 0]; ob[0] = u0 > 0.f ? u0 : 0.f;
    float u1 = accB[1] * inv + bias[cB0 + 1]; ob[1] = u1 > 0.f ? u1 : 0.f;
    *(floatx2*)(out + obase + cB0) = ob;
}

// ---------------------------------------------------------------------- host
extern "C" void kernel_launch(void* const* d_in, const int* in_sizes, int n_in,
                              void* d_out, int out_size, void* d_ws, size_t ws_size,
                              hipStream_t stream) {
    const float* x   = (const float*)d_in[0];
    const int*   ei  = (const int*)d_in[1];
    const float* W1  = (const float*)d_in[2];
    const float* as1 = (const float*)d_in[3];
    const float* ad1 = (const float*)d_in[4];
    const float* b1  = (const float*)d_in[5];
    const float* W2  = (const float*)d_in[6];
    const float* as2 = (const float*)d_in[7];
    const float* ad2 = (const float*)d_in[8];
    const float* b2  = (const float*)d_in[9];
    float* out = (float*)d_out;

    const int N  = in_sizes[0] / 128;   // 20000
    const int E  = in_sizes[1] / 2;     // 320000
    const int ET = E + N;
    const int NB = (N + 255) / 256;
    const int* src = ei;
    const int* dst = ei + E;

    char* ws = (char*)d_ws;
    size_t off = 0;
    auto alloc = [&](size_t bytes) {
        void* p = ws + off;
        off = (off + bytes + 255) & ~(size_t)255;
        return p;
    };
    _Float16* xh    = (_Float16*)alloc((size_t)N * 128 * 2);
    _Float16* xagg  = (_Float16*)alloc((size_t)N * 384 * 2);
    _Float16* x2h   = (_Float16*)alloc((size_t)N * 768 * 2);
    _Float16* h2    = (_Float16*)alloc((size_t)N * 384 * 2);
    _Float16* w1t   = (_Float16*)alloc((size_t)768 * 128 * 2);
    _Float16* w2t   = (_Float16*)alloc((size_t)384 * 768 * 2);
    float* vs1  = (float*)alloc(384 * 4);
    float* vd1  = (float*)alloc(384 * 4);
    float* vs2  = (float*)alloc(768 * 4);
    float* vd2  = (float*)alloc(768 * 4);
    float* alS1 = (float*)alloc((size_t)N * 3 * 4);
    float* alD1 = (float*)alloc((size_t)N * 3 * 4);
    // zero-initialized region: deg | alS2 | alD2 (one memset)
    int*   deg  = (int*)alloc((size_t)N * 4);
    float* alS2 = (float*)alloc((size_t)N * 4);
    float* alD2 = (float*)alloc((size_t)N * 4);
    int* rowptr = (int*)alloc((size_t)(N + 1) * 4);
    int* cursor = (int*)alloc((size_t)N * 4);
    int* bsum   = (int*)alloc(256 * 4);
    int* csrs   = (int*)alloc((size_t)ET * 4);

    hipMemsetAsync(deg, 0, (size_t)((char*)rowptr - (char*)deg), stream);

    // CSR by destination (shared by both layers)
    k_hist<<<(ET + 255) / 256, 256, 0, stream>>>(dst, E, N, deg);
    k_scan1<<<NB, 256, 0, stream>>>(deg, bsum, N);
    k_scan3<<<NB, 256, 0, stream>>>(deg, bsum, NB, rowptr, cursor, N);
    k_scatter<<<(ET + 255) / 256, 256, 0, stream>>>(src, dst, E, N, cursor, csrs);

    // fused weight prep
    k_wprep<<<1541, 256, 0, stream>>>(W1, W2, as1, ad1, as2, ad2,
                                      w1t, w2t, vs1, vd1, vs2, vd2);

    // layer 1
    k_prep1<<<(N + 3) / 4, 256, 0, stream>>>(x, xh, vs1, vd1, alS1, alD1, N);
    k_aggx<<<(N + 3) / 4, 256, 0, stream>>>(xh, alS1, alD1, rowptr, csrs, xagg, N);
    dim3 g1(768 / 128, (N + 127) / 128);
    k_hgemm<_Float16, true><<<g1, 256, 0, stream>>>(xagg, w1t, b1, vs2, vd2,
                                                    alS2, alD2, x2h, N, 768, 128);

    // layer 2
    dim3 g2(384 / 128, (N + 127) / 128);
    k_hgemm<_Float16, false><<<g2, 256, 0, stream>>>(x2h, w2t, nullptr, nullptr,
                                                     nullptr, nullptr, nullptr,
                                                     h2, N, 384, 768);
    k_aggw2<<<N, 256, 0, stream>>>(h2, alS2, alD2, rowptr, csrs, b2, out, N);
}

// Round 12
// 199.565 us; speedup vs baseline: 1.0752x; 1.0711x over previous
//
#include <hip/hip_runtime.h>
#include <hip/hip_bf16.h>

#define NEG_SLOPE 0.2f

typedef _Float16 half8 __attribute__((ext_vector_type(8)));
typedef _Float16 half4v __attribute__((ext_vector_type(4)));
typedef _Float16 half2v __attribute__((ext_vector_type(2)));
typedef float floatx4 __attribute__((ext_vector_type(4)));
typedef float floatx2 __attribute__((ext_vector_type(2)));

// ---------------- fused: CSR histogram (blocks < nbh) + weight prep (rest)
__global__ void k_histwprep(const int* __restrict__ dst, int E, int n, int nbh,
                            int* __restrict__ deg,
                            const float* __restrict__ W1, const float* __restrict__ W2,
                            const float* __restrict__ as1, const float* __restrict__ ad1,
                            const float* __restrict__ as2, const float* __restrict__ ad2,
                            _Float16* __restrict__ w1t, _Float16* __restrict__ w2t,
                            float* __restrict__ vs1, float* __restrict__ vd1,
                            float* __restrict__ vs2, float* __restrict__ vd2) {
    int b = blockIdx.x;
    if (b < nbh) {                       // histogram over E+n edges
        int e = b * 256 + threadIdx.x;
        int ET = E + n;
        if (e >= ET) return;
        int d = (e < E) ? dst[e] : (e - E);
        atomicAdd(&deg[d], 1);
        return;
    }
    b -= nbh;
    if (b < 384) {                       // W1[128][768] -> w1t[768][128]
        int i = b * 256 + threadIdx.x;
        int c = i / 128, r = i % 128;
        w1t[i] = (_Float16)W1[(size_t)r * 768 + c];
    } else if (b < 1536) {               // W2[768][384] -> w2t[384][768]
        int i = (b - 384) * 256 + threadIdx.x;
        int c = i / 768, r = i % 768;
        w2t[i] = (_Float16)W2[(size_t)r * 384 + c];
    } else if (b < 1538) {               // vs1/vd1 (384 outputs)
        int t = (b - 1536) * 256 + threadIdx.x;
        if (t < 384) {
            int h = t >> 7, k = t & 127;
            const float* wr = W1 + (size_t)k * 768 + h * 256;
            const float* ar = as1 + h * 256;
            const float* dr = ad1 + h * 256;
            float s = 0.f, d = 0.f;
            for (int c = 0; c < 256; ++c) { float wv = wr[c]; s += wv * ar[c]; d += wv * dr[c]; }
            vs1[t] = s; vd1[t] = d;
        }
    } else {                             // vs2/vd2 (768 outputs)
        int t = (b - 1538) * 256 + threadIdx.x;
        if (t < 768) {
            const float* wr = W2 + (size_t)t * 384;
            float s = 0.f, d = 0.f;
            for (int c = 0; c < 384; ++c) { float wv = wr[c]; s += wv * as2[c]; d += wv * ad2[c]; }
            vs2[t] = s; vd2[t] = d;
        }
    }
}

// phase 1: per-block sums (coalesced)
__global__ void k_scan1(const int* __restrict__ deg, int* __restrict__ bsum, int n) {
    __shared__ int red[256];
    int t = threadIdx.x, b = blockIdx.x;
    int i = b * 256 + t;
    red[t] = (i < n) ? deg[i] : 0;
    __syncthreads();
    for (int off = 128; off; off >>= 1) {
        if (t < off) red[t] += red[t + off];
        __syncthreads();
    }
    if (t == 0) bsum[b] = red[0];
}

// phase 2+3 fused: every block prefixes the (<=256) block sums itself, then
// does its local inclusive scan + offset -> rowptr/cursor.
__global__ void k_scan3(const int* __restrict__ deg, const int* __restrict__ bsum,
                        int nb, int* __restrict__ rowptr, int* __restrict__ cursor,
                        int n) {
    __shared__ int s[256];
    int t = threadIdx.x, b = blockIdx.x;
    s[t] = (t < nb) ? bsum[t] : 0;
    __syncthreads();
    for (int off = 1; off < 256; off <<= 1) {
        int v = (t >= off) ? s[t - off] : 0;
        __syncthreads();
        s[t] += v;
        __syncthreads();
    }
    int base = (b == 0) ? 0 : s[b - 1];
    __syncthreads();
    int i = b * 256 + t;
    int v = (i < n) ? deg[i] : 0;
    s[t] = v;
    __syncthreads();
    for (int off = 1; off < 256; off <<= 1) {
        int u = (t >= off) ? s[t - off] : 0;
        __syncthreads();
        s[t] += u;
        __syncthreads();
    }
    int incl = s[t];
    if (i < n) {
        rowptr[i] = base + incl - v;
        cursor[i] = base + incl - v;
        if (i == n - 1) rowptr[n] = base + incl;
    }
}

// ------------- fused: scatter (blocks < nbs) + x->fp16 + layer-1 logits
__global__ __launch_bounds__(256) void k_scatterprep1(
        const int* __restrict__ src, const int* __restrict__ dst, int E, int n,
        int nbs, int* __restrict__ cursor, int* __restrict__ csr_src,
        const float* __restrict__ x, _Float16* __restrict__ xh,
        const float* __restrict__ vs, const float* __restrict__ vd,
        float* __restrict__ al_s, float* __restrict__ al_d) {
    int b = blockIdx.x;
    if (b < nbs) {                       // scatter
        int e = b * 256 + threadIdx.x;
        int ET = E + n;
        if (e >= ET) return;
        int s = (e < E) ? src[e] : (e - E);
        int d = (e < E) ? dst[e] : (e - E);
        int pos = atomicAdd(&cursor[d], 1);
        csr_src[pos] = s;
        return;
    }
    // prep1: fp32->fp16 convert + logits (one wave per node)
    int wid = (b - nbs) * 4 + (threadIdx.x >> 6);
    int lane = threadIdx.x & 63;
    if (wid >= n) return;
    float2 f = *(const float2*)(x + (size_t)wid * 128 + lane * 2);
    half2v hv; hv[0] = (_Float16)f.x; hv[1] = (_Float16)f.y;
    *(half2v*)(xh + (size_t)wid * 128 + lane * 2) = hv;
    float aS[3], aD[3];
#pragma unroll
    for (int hh = 0; hh < 3; ++hh) {
        floatx2 v = *(const floatx2*)(vs + hh * 128 + lane * 2);
        floatx2 d = *(const floatx2*)(vd + hh * 128 + lane * 2);
        aS[hh] = f.x * v[0] + f.y * v[1];
        aD[hh] = f.x * d[0] + f.y * d[1];
    }
#pragma unroll
    for (int hh = 0; hh < 3; ++hh)
#pragma unroll
        for (int off = 32; off; off >>= 1) {
            aS[hh] += __shfl_xor(aS[hh], off);
            aD[hh] += __shfl_xor(aD[hh], off);
        }
    if (lane == 0) {
#pragma unroll
        for (int hh = 0; hh < 3; ++hh) { al_s[wid * 3 + hh] = aS[hh]; al_d[wid * 3 + hh] = aD[hh]; }
    }
}

// ---------------------- layer-1 aggregation in INPUT space, inline edge exp
// No-max softmax: logits O(+-3) by Glorot arithmetic -> exp safe; alpha ratio
// identical (validated R6-R11, absmax 2e-3).
__global__ __launch_bounds__(256) void k_aggx(const _Float16* __restrict__ xh,
                                              const float* __restrict__ al_s,
                                              const float* __restrict__ al_d,
                                              const int* __restrict__ rowptr,
                                              const int* __restrict__ csr_src,
                                              _Float16* __restrict__ xagg,
                                              int n) {
    int wid = (blockIdx.x * blockDim.x + threadIdx.x) >> 6;
    int lane = threadIdx.x & 63;
    if (wid >= n) return;
    int beg = rowptr[wid], end = rowptr[wid + 1];
    int slot = lane >> 4;     // 0..3  (edge within group)
    int chunk = lane & 15;    // channel chunk

    float ald0 = al_d[wid * 3 + 0], ald1 = al_d[wid * 3 + 1], ald2 = al_d[wid * 3 + 2];

    float acc0[8] = {}, acc1[8] = {}, acc2[8] = {};
    float sw0 = 0.f, sw1 = 0.f, sw2 = 0.f;

    for (int base = beg; base < end; base += 8) {
        int eA = base + slot, eB = base + 4 + slot;
        bool vA = eA < end, vB = eB < end;
        int sA = vA ? csr_src[eA] : 0;
        int sB = vB ? csr_src[eB] : 0;
        float wA0 = 0.f, wA1 = 0.f, wA2 = 0.f, wB0 = 0.f, wB1 = 0.f, wB2 = 0.f;
        if (vA) {
            float e0 = al_s[sA * 3 + 0] + ald0; e0 = e0 > 0.f ? e0 : NEG_SLOPE * e0;
            float e1 = al_s[sA * 3 + 1] + ald1; e1 = e1 > 0.f ? e1 : NEG_SLOPE * e1;
            float e2 = al_s[sA * 3 + 2] + ald2; e2 = e2 > 0.f ? e2 : NEG_SLOPE * e2;
            wA0 = __expf(e0); wA1 = __expf(e1); wA2 = __expf(e2);
        }
        if (vB) {
            float e0 = al_s[sB * 3 + 0] + ald0; e0 = e0 > 0.f ? e0 : NEG_SLOPE * e0;
            float e1 = al_s[sB * 3 + 1] + ald1; e1 = e1 > 0.f ? e1 : NEG_SLOPE * e1;
            float e2 = al_s[sB * 3 + 2] + ald2; e2 = e2 > 0.f ? e2 : NEG_SLOPE * e2;
            wB0 = __expf(e0); wB1 = __expf(e1); wB2 = __expf(e2);
        }
        sw0 += wA0 + wB0; sw1 += wA1 + wB1; sw2 += wA2 + wB2;
        half8 xvA = *(const half8*)(xh + (size_t)sA * 128 + chunk * 8);
        half8 xvB = *(const half8*)(xh + (size_t)sB * 128 + chunk * 8);
#pragma unroll
        for (int k = 0; k < 8; ++k) {
            float fA = (float)xvA[k], fB = (float)xvB[k];
            acc0[k] = fmaf(wA0, fA, acc0[k]); acc0[k] = fmaf(wB0, fB, acc0[k]);
            acc1[k] = fmaf(wA1, fA, acc1[k]); acc1[k] = fmaf(wB1, fB, acc1[k]);
            acc2[k] = fmaf(wA2, fA, acc2[k]); acc2[k] = fmaf(wB2, fB, acc2[k]);
        }
    }
#pragma unroll
    for (int k = 0; k < 8; ++k) {
        acc0[k] += __shfl_xor(acc0[k], 16); acc0[k] += __shfl_xor(acc0[k], 32);
        acc1[k] += __shfl_xor(acc1[k], 16); acc1[k] += __shfl_xor(acc1[k], 32);
        acc2[k] += __shfl_xor(acc2[k], 16); acc2[k] += __shfl_xor(acc2[k], 32);
    }
    sw0 += __shfl_xor(sw0, 16); sw0 += __shfl_xor(sw0, 32);
    sw1 += __shfl_xor(sw1, 16); sw1 += __shfl_xor(sw1, 32);
    sw2 += __shfl_xor(sw2, 16); sw2 += __shfl_xor(sw2, 32);

    if (lane < 16) {
        float i0 = 1.f / sw0, i1 = 1.f / sw1, i2 = 1.f / sw2;
        _Float16* op = xagg + (size_t)wid * 384 + chunk * 8;
        half8 o0, o1, o2;
#pragma unroll
        for (int k = 0; k < 8; ++k) {
            o0[k] = (_Float16)(acc0[k] * i0);
            o1[k] = (_Float16)(acc1[k] * i1);
            o2[k] = (_Float16)(acc2[k] * i2);
        }
        *(half8*)(op + 0)   = o0;
        *(half8*)(op + 128) = o1;
        *(half8*)(op + 256) = o2;
    }
}

// ------------------------------------------------------------ fp16 MFMA GEMM
// GAT=true (layer 1): A = xagg[M][3][128], head = col/256; epilogue bias+ReLU,
//   writes x2h fp16 + accumulates layer-2 logits via atomics.
// GAT=false (layer 2): plain C = A @ Bt^T, row-major fp16 out.
__device__ __forceinline__ void gload_lds16(const _Float16* g, _Float16* l) {
    __builtin_amdgcn_global_load_lds((const __attribute__((address_space(1))) void*)g,
                                     (__attribute__((address_space(3))) void*)l,
                                     16, 0, 0);
}

template <typename OutT, bool GAT>
__global__ __launch_bounds__(256) void k_hgemm(const _Float16* __restrict__ A,
                                               const _Float16* __restrict__ Bt,
                                               const float* __restrict__ bias,
                                               const float* __restrict__ vs2,
                                               const float* __restrict__ vd2,
                                               float* __restrict__ alS2,
                                               float* __restrict__ alD2,
                                               OutT* __restrict__ C,
                                               int M, int N, int K) {
    __shared__ _Float16 lds[2 * 8192];
    int t = threadIdx.x;
    int lane = t & 63, w = t >> 6;
    int wr = w >> 1, wc = w & 1;
    int lrow = lane & 15, lko = lane >> 4;
    int row0 = blockIdx.y * 128, col0 = blockIdx.x * 128;

    int sr = t & 127;
    int sko = t >> 7;
    int agr = row0 + sr; if (agr >= M) agr = M - 1;
    const _Float16* aRow;
    if constexpr (GAT) {
        int head = col0 >> 8;
        aRow = A + (size_t)agr * 384 + head * 128;
    } else {
        aRow = A + (size_t)agr * K;
    }
    const _Float16* bRow = Bt + (size_t)(col0 + sr) * K;

    floatx4 acc[4][4] = {};

    int nk = K >> 5;
#pragma unroll
    for (int s = 0; s < 2; ++s) {
        int ko = s * 2 + sko;
        gload_lds16(aRow + ko * 8, lds + s * 2048 + t * 8);
        gload_lds16(bRow + ko * 8, lds + 4096 + s * 2048 + t * 8);
    }
    __syncthreads();

    for (int ks = 0; ks < nk; ++ks) {
        int buf = ks & 1;
        if (ks + 1 < nk) {
            int kt = (ks + 1) << 5;
            _Float16* dstb = lds + (buf ^ 1) * 8192;
#pragma unroll
            for (int s = 0; s < 2; ++s) {
                int ko = s * 2 + sko;
                gload_lds16(aRow + kt + ko * 8, dstb + s * 2048 + t * 8);
                gload_lds16(bRow + kt + ko * 8, dstb + 4096 + s * 2048 + t * 8);
            }
        }
        const _Float16* base = lds + buf * 8192 + lko * 1024;
        half8 af[4], bf[4];
#pragma unroll
        for (int mi = 0; mi < 4; ++mi)
            af[mi] = *(const half8*)(base + (wr * 64 + mi * 16 + lrow) * 8);
#pragma unroll
        for (int ni = 0; ni < 4; ++ni)
            bf[ni] = *(const half8*)(base + 4096 + (wc * 64 + ni * 16 + lrow) * 8);
#pragma unroll
        for (int mi = 0; mi < 4; ++mi)
#pragma unroll
            for (int ni = 0; ni < 4; ++ni)
                acc[mi][ni] = __builtin_amdgcn_mfma_f32_16x16x32_f16(
                    af[mi], bf[ni], acc[mi][ni], 0, 0, 0);
        __syncthreads();
    }

#pragma unroll
    for (int mi = 0; mi < 4; ++mi) {
#pragma unroll
        for (int j = 0; j < 4; ++j) {
            int row = row0 + wr * 64 + mi * 16 + lko * 4 + j;
            float ps = 0.f, pd = 0.f;
#pragma unroll
            for (int ni = 0; ni < 4; ++ni) {
                int col = col0 + wc * 64 + ni * 16 + lrow;
                float v = acc[mi][ni][j];
                if constexpr (GAT) {
                    v += bias[col]; v = v > 0.f ? v : 0.f;
                    ps = fmaf(v, vs2[col], ps);
                    pd = fmaf(v, vd2[col], pd);
                }
                if (row < M) C[(size_t)row * N + col] = (OutT)v;
            }
            if constexpr (GAT) {
                if (row >= M) { ps = 0.f; pd = 0.f; }
#pragma unroll
                for (int off = 1; off < 16; off <<= 1) {
                    ps += __shfl_xor(ps, off);
                    pd += __shfl_xor(pd, off);
                }
                if (lrow == 0 && row < M) {
                    atomicAdd(&alS2[row], ps);
                    atomicAdd(&alD2[row], pd);
                }
            }
        }
    }
}

// -------- layer-2 gather-agg (R9-measured-best): 2 waves/node, inline exp
__global__ __launch_bounds__(256) void k_aggw2(const _Float16* __restrict__ h,
                                               const float* __restrict__ al_s,
                                               const float* __restrict__ al_d,
                                               const int* __restrict__ rowptr,
                                               const int* __restrict__ csr_src,
                                               const float* __restrict__ bias,
                                               float* __restrict__ out, int n) {
    constexpr int HC = 384;
    constexpr int CA = 4;
    constexpr int CB = 2;
    int wv = threadIdx.x >> 6;
    int lane = threadIdx.x & 63;
    int node = blockIdx.x * 2 + (wv >> 1);
    int half = wv & 1;
    int ns = wv >> 1;

    __shared__ float s_acc[2][64][CA + CB];
    __shared__ float s_sw[2];

    int beg = rowptr[node], end = rowptr[node + 1];
    float ald = al_d[node];

    float accA[CA] = {}, accB[CB] = {};
    float swsum = 0.f;

    for (int base = beg + half; base < end; base += 128) {
        int myi = base + 2 * lane;
        bool valid = myi < end;
        int sl = valid ? csr_src[myi] : 0;
        float wl = 0.f;
        if (valid) {
            float e = al_s[sl] + ald;
            e = e > 0.f ? e : NEG_SLOPE * e;
            wl = __expf(e);
        }
        swsum += wl;
        int cnt = min(64, (end - base + 1) >> 1);
        int j = 0;
        for (; j + 4 <= cnt; j += 4) {
            int ss0 = __shfl(sl, j + 0), ss1 = __shfl(sl, j + 1);
            int ss2 = __shfl(sl, j + 2), ss3 = __shfl(sl, j + 3);
            float wA0 = __shfl(wl, j + 0), wA1 = __shfl(wl, j + 1);
            float wA2 = __shfl(wl, j + 2), wA3 = __shfl(wl, j + 3);
            const _Float16* r0 = h + (size_t)ss0 * HC;
            const _Float16* r1 = h + (size_t)ss1 * HC;
            const _Float16* r2 = h + (size_t)ss2 * HC;
            const _Float16* r3 = h + (size_t)ss3 * HC;
            half4v va0 = *(const half4v*)(r0 + lane * 4);
            half4v va1 = *(const half4v*)(r1 + lane * 4);
            half4v va2 = *(const half4v*)(r2 + lane * 4);
            half4v va3 = *(const half4v*)(r3 + lane * 4);
            half2v vb0 = *(const half2v*)(r0 + 256 + lane * 2);
            half2v vb1 = *(const half2v*)(r1 + 256 + lane * 2);
            half2v vb2 = *(const half2v*)(r2 + 256 + lane * 2);
            half2v vb3 = *(const half2v*)(r3 + 256 + lane * 2);
#pragma unroll
            for (int k = 0; k < 4; ++k) {
                accA[k] = fmaf(wA0, (float)va0[k], accA[k]);
                accA[k] = fmaf(wA1, (float)va1[k], accA[k]);
                accA[k] = fmaf(wA2, (float)va2[k], accA[k]);
                accA[k] = fmaf(wA3, (float)va3[k], accA[k]);
            }
#pragma unroll
            for (int k = 0; k < 2; ++k) {
                accB[k] = fmaf(wA0, (float)vb0[k], accB[k]);
                accB[k] = fmaf(wA1, (float)vb1[k], accB[k]);
                accB[k] = fmaf(wA2, (float)vb2[k], accB[k]);
                accB[k] = fmaf(wA3, (float)vb3[k], accB[k]);
            }
        }
        for (; j < cnt; ++j) {
            int s = __shfl(sl, j);
            float aA = __shfl(wl, j);
            const _Float16* row = h + (size_t)s * HC;
            half4v va = *(const half4v*)(row + lane * 4);
            half2v vb = *(const half2v*)(row + 256 + lane * 2);
#pragma unroll
            for (int k = 0; k < 4; ++k) accA[k] = fmaf(aA, (float)va[k], accA[k]);
#pragma unroll
            for (int k = 0; k < 2; ++k) accB[k] = fmaf(aA, (float)vb[k], accB[k]);
        }
    }

#pragma unroll
    for (int off = 32; off; off >>= 1) swsum += __shfl_xor(swsum, off);

    if (half == 1) {
#pragma unroll
        for (int k = 0; k < CA; ++k) s_acc[ns][lane][k] = accA[k];
#pragma unroll
        for (int k = 0; k < CB; ++k) s_acc[ns][lane][CA + k] = accB[k];
        if (lane == 0) s_sw[ns] = swsum;
    }
    __syncthreads();
    if (half == 1) return;

#pragma unroll
    for (int k = 0; k < CA; ++k) accA[k] += s_acc[ns][lane][k];
#pragma unroll
    for (int k = 0; k < CB; ++k) accB[k] += s_acc[ns][lane][CA + k];
    float inv = 1.f / (swsum + s_sw[ns]);

    size_t obase = (size_t)node * HC;
    int cA0 = lane * CA, cB0 = 64 * CA + lane * CB;
    float4 oa;
    float t0 = accA[0] * inv + bias[cA0 + 0]; oa.x = t0 > 0.f ? t0 : 0.f;
    float t1 = accA[1] * inv + bias[cA0 + 1]; oa.y = t1 > 0.f ? t1 : 0.f;
    float t2 = accA[2] * inv + bias[cA0 + 2]; oa.z = t2 > 0.f ? t2 : 0.f;
    float t3 = accA[3] * inv + bias[cA0 + 3]; oa.w = t3 > 0.f ? t3 : 0.f;
    *(float4*)(out + obase + cA0) = oa;
    floatx2 ob;
    float u0 = accB[0] * inv + bias[cB0 + 0]; ob[0] = u0 > 0.f ? u0 : 0.f;
    float u1 = accB[1] * inv + bias[cB0 + 1]; ob[1] = u1 > 0.f ? u1 : 0.f;
    *(floatx2*)(out + obase + cB0) = ob;
}

// ---------------------------------------------------------------------- host
extern "C" void kernel_launch(void* const* d_in, const int* in_sizes, int n_in,
                              void* d_out, int out_size, void* d_ws, size_t ws_size,
                              hipStream_t stream) {
    const float* x   = (const float*)d_in[0];
    const int*   ei  = (const int*)d_in[1];
    const float* W1  = (const float*)d_in[2];
    const float* as1 = (const float*)d_in[3];
    const float* ad1 = (const float*)d_in[4];
    const float* b1  = (const float*)d_in[5];
    const float* W2  = (const float*)d_in[6];
    const float* as2 = (const float*)d_in[7];
    const float* ad2 = (const float*)d_in[8];
    const float* b2  = (const float*)d_in[9];
    float* out = (float*)d_out;

    const int N  = in_sizes[0] / 128;   // 20000
    const int E  = in_sizes[1] / 2;     // 320000
    const int ET = E + N;
    const int NB  = (N + 255) / 256;    // 79 scan blocks
    const int NBE = (ET + 255) / 256;   // 1329 edge blocks
    const int* src = ei;
    const int* dst = ei + E;

    char* ws = (char*)d_ws;
    size_t off = 0;
    auto alloc = [&](size_t bytes) {
        void* p = ws + off;
        off = (off + bytes + 255) & ~(size_t)255;
        return p;
    };
    _Float16* xh    = (_Float16*)alloc((size_t)N * 128 * 2);
    _Float16* xagg  = (_Float16*)alloc((size_t)N * 384 * 2);
    _Float16* x2h   = (_Float16*)alloc((size_t)N * 768 * 2);
    _Float16* h2    = (_Float16*)alloc((size_t)N * 384 * 2);
    _Float16* w1t   = (_Float16*)alloc((size_t)768 * 128 * 2);
    _Float16* w2t   = (_Float16*)alloc((size_t)384 * 768 * 2);
    float* vs1  = (float*)alloc(384 * 4);
    float* vd1  = (float*)alloc(384 * 4);
    float* vs2  = (float*)alloc(768 * 4);
    float* vd2  = (float*)alloc(768 * 4);
    float* alS1 = (float*)alloc((size_t)N * 3 * 4);
    float* alD1 = (float*)alloc((size_t)N * 3 * 4);
    // zero-initialized region: deg | alS2 | alD2 (one memset)
    int*   deg  = (int*)alloc((size_t)N * 4);
    float* alS2 = (float*)alloc((size_t)N * 4);
    float* alD2 = (float*)alloc((size_t)N * 4);
    int* rowptr = (int*)alloc((size_t)(N + 1) * 4);
    int* cursor = (int*)alloc((size_t)N * 4);
    int* bsum   = (int*)alloc(256 * 4);
    int* csrs   = (int*)alloc((size_t)ET * 4);

    hipMemsetAsync(deg, 0, (size_t)((char*)rowptr - (char*)deg), stream);

    // histogram + weight prep (independent work, one dispatch)
    k_histwprep<<<NBE + 1541, 256, 0, stream>>>(dst, E, N, NBE, deg,
                                                W1, W2, as1, ad1, as2, ad2,
                                                w1t, w2t, vs1, vd1, vs2, vd2);
    k_scan1<<<NB, 256, 0, stream>>>(deg, bsum, N);
    k_scan3<<<NB, 256, 0, stream>>>(deg, bsum, NB, rowptr, cursor, N);
    // scatter + x-convert + layer-1 logits (one dispatch)
    k_scatterprep1<<<NBE + (N + 3) / 4, 256, 0, stream>>>(
        src, dst, E, N, NBE, cursor, csrs, x, xh, vs1, vd1, alS1, alD1);

    // layer 1
    k_aggx<<<(N + 3) / 4, 256, 0, stream>>>(xh, alS1, alD1, rowptr, csrs, xagg, N);
    dim3 g1(768 / 128, (N + 127) / 128);
    k_hgemm<_Float16, true><<<g1, 256, 0, stream>>>(xagg, w1t, b1, vs2, vd2,
                                                    alS2, alD2, x2h, N, 768, 128);

    // layer 2
    dim3 g2(384 / 128, (N + 127) / 128);
    k_hgemm<_Float16, false><<<g2, 256, 0, stream>>>(x2h, w2t, nullptr, nullptr,
                                                     nullptr, nullptr, nullptr,
                                                     h2, N, 384, 768);
    k_aggw2<<<N / 2, 256, 0, stream>>>(h2, alS2, alD2, rowptr, csrs, b2, out, N);
}